// Round 16
// baseline (516.762 us; speedup 1.0000x reference)
//
#include <hip/hip_runtime.h>
#include <hip/hip_bf16.h>

#define BB 2
#define SS 513
#define HH 512
#define NHH 8
#define DDIM 64

typedef float f32x4v __attribute__((ext_vector_type(4)));
typedef int i32x4v __attribute__((ext_vector_type(4)));
typedef unsigned short ushort_t;

// ---- workspace offsets (bytes) ----
#define OFF_VSUM   256
#define OFF_XSUM   4608                              // 8 partials * 5120 f32 = 160 KB
#define OFF_QP     172032
#define OFF_KP     (172032 + 2101248)
#define OFF_VP     (172032 + 2 * 2101248)
#define OFF_XPP    (172032 + 3 * 2101248)
#define OFF_WBF    (172032 + 4 * 2101248)            // 8577024
#define WS_NEED    (8577024ULL + 16777216ULL)        // 25.35 MB

__device__ __forceinline__ float dot4(float4 a, float4 b) {
  return a.x * b.x + a.y * b.y + a.z * b.z + a.w * b.w;
}
__device__ __forceinline__ float4 add4(float4 a, float4 b) {
  return make_float4(a.x + b.x, a.y + b.y, a.z + b.z, a.w + b.w);
}

#define DPP_ADD(v, ctrl) \
  ((v) + __int_as_float(__builtin_amdgcn_update_dpp( \
             0, __float_as_int(v), (ctrl), 0xF, 0xF, true)))
__device__ __forceinline__ float kg_reduce8(float v) {
  v = DPP_ADD(v, 0xB1);
  v = DPP_ADD(v, 0x4E);
  v = DPP_ADD(v, 0x141);
  return v;
}

__device__ __forceinline__ bool graph_at(const void* g, int isBool, size_t idx) {
  if (isBool) return ((const unsigned char*)g)[idx] != 0;
  return ((const int*)g)[idx] != 0;
}

// ---- bf16 helpers (RNE) — numerics verified rounds 9-15 ----
__device__ __forceinline__ unsigned int f2bf(float f) {
  unsigned int u = __float_as_uint(f);
  return (u + 0x7FFFu + ((u >> 16) & 1u)) >> 16;
}
__device__ __forceinline__ float bf2f(unsigned int h) {
  return __uint_as_float(h << 16);
}
__device__ __forceinline__ void split8(f32x4v a, f32x4v b, i32x4v& hi, i32x4v& lo) {
  float v[8] = {a[0], a[1], a[2], a[3], b[0], b[1], b[2], b[3]};
  unsigned int h[8], l[8];
#pragma unroll
  for (int j = 0; j < 8; ++j) {
    h[j] = f2bf(v[j]);
    l[j] = f2bf(v[j] - bf2f(h[j]));
  }
  hi[0] = (int)(h[0] | (h[1] << 16)); hi[1] = (int)(h[2] | (h[3] << 16));
  hi[2] = (int)(h[4] | (h[5] << 16)); hi[3] = (int)(h[6] | (h[7] << 16));
  lo[0] = (int)(l[0] | (l[1] << 16)); lo[1] = (int)(l[2] | (l[3] << 16));
  lo[2] = (int)(l[4] | (l[5] << 16)); lo[3] = (int)(l[6] | (l[7] << 16));
}
__device__ __forceinline__ void mfma_bf16(f32x4v& acc, i32x4v a, i32x4v b) {
  asm("v_mfma_f32_16x16x32_bf16 %0, %1, %2, %0" : "+v"(acc) : "v"(a), "v"(b));
}

__device__ __forceinline__ int trow(int f, int i) {
  return (f < 3) ? (f + 9 * i) : (f + 2 * (i % 3) + 9 * (i / 3));
}

// ---------------------------------------------------------------------------
// Timing marker: spins ~ticks/100MHz wall-clock. Durations chosen > harness
// fill kernels (75.7us) so all 5 markers land in the rocprof top-5 with
// timestamps; inter-marker gaps = per-kernel durations. Diagnostic round.
__global__ __launch_bounds__(64) void marker_kernel(long long ticks) {
  long long t0 = __builtin_amdgcn_s_memrealtime();
  while (__builtin_amdgcn_s_memrealtime() - t0 < ticks)
    __builtin_amdgcn_s_sleep(2);
}

// ---------------------------------------------------------------------------
// P1: blocks [0,2048) conv W -> bf16 fragments (coalesced loads+stores);
// [2048,2128) xsumV partials; block 2128 = graph layout detect.
__global__ __launch_bounds__(256) void prepare_kernel(
    const float* __restrict__ Wq, const float* __restrict__ Wk,
    const float* __restrict__ Wv, const float* __restrict__ Wo,
    ushort_t* __restrict__ WBF,
    const float* __restrict__ value, float* __restrict__ xsumVp,
    const uint4* __restrict__ gv, int* __restrict__ flag) {
  const int bid = blockIdx.x;
  const int tid = threadIdx.x;
  if (bid < 2048) {
    const int tf = bid >> 7;                 // 0..15
    const int mt = (bid >> 2) & 31;          // 0..31
    const int ksg = bid & 3;                 // 0..3
    const int w = tid >> 6, l = tid & 63;
    const int ks = ksg * 4 + w;              // 0..15
    const int m = l & 15, kq = l >> 4;
    const float* wrow;
    if (tf < 15) {
      const int t = tf / 5, f = tf % 5;
      const float* W = (t == 0) ? Wq : (t == 1) ? Wk : Wv;
      wrow = W + ((size_t)f * HH + mt * 16 + m) * HH;
    } else {
      wrow = Wo + (size_t)(mt * 16 + m) * HH;
    }
    const float* src = wrow + ks * 32 + kq * 8;
    f32x4v a = *(const f32x4v*)src;
    f32x4v b = *(const f32x4v*)(src + 4);
    i32x4v hi, lo;
    split8(a, b, hi, lo);
    ushort_t* dst = WBF + (size_t)tf * 524288 + (size_t)mt * 16384 + ks * 1024 + l * 8;
    *(i32x4v*)dst = hi;
    *(i32x4v*)(dst + 512) = lo;
  } else if (bid < 2128) {
    const int blk = bid - 2048;
    const int p = blk & 7, combo = blk >> 3;
    const int b = combo / 5, f = combo % 5;
    const int count = (f < 3) ? 57 : 171;
    float a0 = 0.f, a1 = 0.f;
    for (int i = p; i < count; i += 8) {
      const float* vr = value + (size_t)(b * SS + trow(f, i)) * HH;
      a0 += vr[tid];
      a1 += vr[tid + 256];
    }
    float* dst = xsumVp + p * 5120 + combo * HH;
    dst[tid] = a0;
    dst[tid + 256] = a1;
  } else {
    __shared__ int s;
    if (tid == 0) s = 0;
    __syncthreads();
    unsigned int local = 0;
    for (int i = tid; i < 2048; i += 256) {  // 32 KB scan
      uint4 v = gv[i];
      local |= (v.x | v.y | v.z | v.w) & 0x0000ff00u;
    }
    if (local) atomicOr(&s, 1);
    __syncthreads();
    if (tid == 0) *flag = s;
  }
}

// ---------------------------------------------------------------------------
// P2: prep GEMM, 256-thr blocks with mh-split (2x blocks vs r15 for latency
// hiding), XCD-pinned (bid&7 = XCD). grid = 8 x 30 = 240.
// xcd 0-5: big tf (22 slots: 11 nb x 2 mh) + small tf (8 slots: 4 nb x 2 mh).
// xcd 6: tf 10/11/12 (24 slots) + 6 vsum units; xcd 7: 26 vsum units.
__global__ __launch_bounds__(256) void gemm_prep_kernel(
    const ushort_t* __restrict__ WBF,
    const float* __restrict__ Xq, const float* __restrict__ Xk,
    const float* __restrict__ Xv,
    const float* __restrict__ Bq, const float* __restrict__ Bk,
    const float* __restrict__ Bv,
    const float* __restrict__ WvF, const float* __restrict__ xsumVp,
    float* __restrict__ Yq, float* __restrict__ Yk, float* __restrict__ Yv,
    float* __restrict__ vsum) {
  __shared__ ushort_t sX[32768];  // 64 KB
  const int tid = threadIdx.x;
  const int xcd = blockIdx.x & 7, slot = blockIdx.x >> 3;   // slot 0..29

  int gvb = -1;
  if (xcd == 6 && slot >= 24) gvb = slot - 24;               // 0..5
  else if (xcd == 7) {
    if (slot >= 26) return;
    gvb = 6 + slot;                                          // 6..31
  }

  if (gvb >= 0) {
    // ---- V-sum GEMV unit: 32 outputs (verified rounds 11-15) ----
    float* ldsx = (float*)sX;  // 20 KB
    for (int j = tid; j < 5120; j += 256) {
      float s = 0.f;
#pragma unroll
      for (int p = 0; p < 8; ++p) s += xsumVp[p * 5120 + j];
      ldsx[j] = s;
    }
    __syncthreads();
    const int wv2 = tid >> 6, lane = tid & 63, og = lane >> 3, kg = lane & 7;
    const int oid = gvb * 32 + wv2 * 8 + og;
    const int b = oid >> 9, o = oid & 511;
    float acc = 0.f;
#pragma unroll
    for (int f = 0; f < 5; ++f) {
      const float* wr = WvF + ((size_t)f * HH + o) * HH + kg * 4;
      const float* xr = ldsx + b * 2560 + f * 512 + kg * 4;
#pragma unroll
      for (int i2 = 0; i2 < 16; ++i2)
        acc += dot4(*(const float4*)(wr + i2 * 32), *(const float4*)(xr + i2 * 32));
    }
    acc = kg_reduce8(acc);
    if (kg == 0) {
      float bs = 0.f;
#pragma unroll
      for (int ff = 0; ff < 5; ++ff) bs += Bv[ff * HH + o];
      vsum[oid] = acc + 513.0f * bs;
    }
    return;
  }

  int tf, nb, mh;
  if (xcd < 6) {
    const int tfBig[6] = {3, 4, 8, 9, 13, 14};
    const int tfSml[6] = {0, 1, 2, 5, 6, 7};
    if (slot < 22) { tf = tfBig[xcd]; nb = slot >> 1; mh = slot & 1; }
    else           { int u = slot - 22; tf = tfSml[xcd]; nb = u >> 1; mh = u & 1; }
  } else {  // xcd == 6, slot < 24
    const int tfX[3] = {10, 11, 12};
    tf = tfX[slot >> 3];
    const int u = slot & 7;
    nb = u >> 1; mh = u & 1;
  }
  const int t = tf / 5, f = tf % 5;
  const int count = (f < 3) ? 57 : 171, ng = 2 * count;
  const float* X = (t == 0) ? Xq : (t == 1) ? Xk : Xv;

  // ---- inline stage+convert 32 X rows -> bf16 hi/lo fragments in LDS ----
#pragma unroll
  for (int j = 0; j < 8; ++j) {
    const int uid = tid + j * 256;
    const int rr = uid >> 6, kc = uid & 63;
    const int gi = nb * 32 + rr;
    f32x4v a = {0.f, 0.f, 0.f, 0.f}, b2 = {0.f, 0.f, 0.f, 0.f};
    if (gi < ng) {
      const int bb = (gi >= count) ? 1 : 0, i = gi - bb * count;
      const float* xr = X + (size_t)(bb * SS + trow(f, i)) * HH + kc * 8;
      a = *(const f32x4v*)xr;
      b2 = *(const f32x4v*)(xr + 4);
    }
    i32x4v hi, lo;
    split8(a, b2, hi, lo);
    const int nt = rr >> 4, n = rr & 15, ks = kc >> 2, kq2 = kc & 3;
    const int dst = nt * 16384 + ks * 1024 + (kq2 * 16 + n) * 8;
    *(i32x4v*)(sX + dst) = hi;
    *(i32x4v*)(sX + dst + 512) = lo;
  }
  __syncthreads();

  const int wid = tid >> 6, l = tid & 63, kq = l >> 4, col = l & 15;
  const int mt0 = mh * 16 + wid * 4;
  const ushort_t* Abase = WBF + (size_t)tf * 524288 + (size_t)mt0 * 16384;

  f32x4v acc0[4][2], acc1[4][2];
#pragma unroll
  for (int w = 0; w < 4; ++w)
#pragma unroll
    for (int tau = 0; tau < 2; ++tau) {
      acc0[w][tau] = (f32x4v){0.f, 0.f, 0.f, 0.f};
      acc1[w][tau] = (f32x4v){0.f, 0.f, 0.f, 0.f};
    }

#pragma unroll
  for (int ks = 0; ks < 16; ++ks) {
    const ushort_t* b0 = sX + ks * 1024 + l * 8;
    i32x4v bhi0 = *(const i32x4v*)b0;
    i32x4v blo0 = *(const i32x4v*)(b0 + 512);
    i32x4v bhi1 = *(const i32x4v*)(b0 + 16384);
    i32x4v blo1 = *(const i32x4v*)(b0 + 16384 + 512);
#pragma unroll
    for (int w = 0; w < 4; ++w) {
      const ushort_t* ap = Abase + (size_t)w * 16384 + ks * 1024 + l * 8;
      i32x4v ahi = *(const i32x4v*)ap;
      i32x4v alo = *(const i32x4v*)(ap + 512);
      mfma_bf16(acc0[w][0], ahi, bhi0);
      mfma_bf16(acc1[w][0], ahi, blo0);
      mfma_bf16(acc1[w][0], alo, bhi0);
      mfma_bf16(acc0[w][1], ahi, bhi1);
      mfma_bf16(acc1[w][1], ahi, blo1);
      mfma_bf16(acc1[w][1], alo, bhi1);
    }
  }

  const float* Bi = (t == 0) ? Bq : (t == 1) ? Bk : Bv;
  float* Y = (t == 0) ? Yq : (t == 1) ? Yk : Yv;
#pragma unroll
  for (int w = 0; w < 4; ++w) {
    const int o0 = (mt0 + w) * 16 + kq * 4;
    f32x4v bs = {0.f, 0.f, 0.f, 0.f};
#pragma unroll
    for (int ff = 0; ff < 5; ++ff) bs += *(const f32x4v*)(Bi + ff * HH + o0);
#pragma unroll
    for (int tau = 0; tau < 2; ++tau) {
      const int gi = nb * 32 + tau * 16 + col;
      if (gi < ng) {
        const int bb = (gi >= count) ? 1 : 0, i = gi - bb * count;
        f32x4v r = acc0[w][tau] + acc1[w][tau] + bs;
        *(f32x4v*)(Y + (size_t)(bb * SS + trow(f, i)) * HH + o0) = r;
      }
    }
  }
}

// ---------------------------------------------------------------------------
// P3: fused attention. blocks [0,1020) sparse q>=3; [1020,1068) dense (b,q,h).
__global__ __launch_bounds__(256) void attn_fused_kernel(
    const float* __restrict__ Q, const float* __restrict__ K, const float* __restrict__ V,
    const float* __restrict__ vsum, const void* __restrict__ graph,
    const int* __restrict__ flag,
    const float* __restrict__ EK, const float* __restrict__ EV, const float* __restrict__ EQ,
    float* __restrict__ X) {
  __shared__ float sA[520];
  __shared__ float sB[1024];
  __shared__ float sW[5 * NHH];
  __shared__ float red[8];
  __shared__ int sUni;

  const int tid = threadIdx.x, lane = tid & 63, wv = tid >> 6;
  const int isBool = *flag;

  if (blockIdx.x < 1020) {
    // ---------------- sparse path ----------------
    const int bid = blockIdx.x;
    const int b = bid / 510, q = 3 + bid % 510;
    const int row = b * SS + q;

    sA[tid] = Q[(size_t)row * HH + tid];
    sA[tid + 256] = Q[(size_t)row * HH + tid + 256];
    if (tid == 0) sUni = 0;
    __syncthreads();

    const int g = 3 + ((q - 3) >> 1) * 2;
    const size_t gbase = (size_t)b * SS * SS + (size_t)q * SS;
    const int h = lane >> 3, dg = lane & 7, d0 = dg * 8;

    for (int c = wv; c < 5; c += 4) {
      int k = (c < 3) ? c : g + (c - 3);
      bool m = graph_at(graph, isBool, gbase + k);
      const float* ekp = EK + (gbase + k) * DDIM + d0;
      const float* eqp = EQ + ((size_t)(b * SS + k) * SS + q) * DDIM + d0;
      const float* kp  = K + (size_t)(b * SS + k) * HH + h * 64 + d0;
      const float* qp  = &sA[h * 64 + d0];
      float4 ek0 = *(const float4*)ekp, ek1 = *(const float4*)(ekp + 4);
      float4 eq0 = *(const float4*)eqp, eq1 = *(const float4*)(eqp + 4);
      float4 kk0 = *(const float4*)kp,  kk1 = *(const float4*)(kp + 4);
      float4 qq0 = *(const float4*)qp,  qq1 = *(const float4*)(qp + 4);
      float p = dot4(add4(qq0, eq0), add4(kk0, ek0)) + dot4(add4(qq1, eq1), add4(kk1, ek1));
      p += __shfl_xor(p, 1);
      p += __shfl_xor(p, 2);
      p += __shfl_xor(p, 4);
      if (dg == 0) sW[c * NHH + h] = m ? p * 0.125f : -1e30f;
    }
    __syncthreads();

    if (wv == 0) {
      int hh = lane >> 3, c = lane & 7;
      float s = (c < 5) ? sW[c * NHH + hh] : -1e30f;
      float mx = s;
#pragma unroll
      for (int off = 4; off; off >>= 1) mx = fmaxf(mx, __shfl_xor(mx, off));
      float e = (mx < -1e29f) ? 0.f : __expf(s - mx);
      float sum = e;
#pragma unroll
      for (int off = 4; off; off >>= 1) sum += __shfl_xor(sum, off);
      if (c < 5) sW[c * NHH + hh] = (mx < -1e29f) ? 0.f : e / sum;
      if (lane == 0 && mx < -1e29f) sUni = 1;
    }
    __syncthreads();

    if (sUni) {
      float acc = 0.f;
      for (int k = wv; k < SS; k += 4)
        acc += EV[(gbase + k) * DDIM + lane];
      sB[wv * 64 + lane] = acc;
      __syncthreads();
      if (tid < 64) sB[tid] = sB[tid] + sB[64 + tid] + sB[128 + tid] + sB[192 + tid];
      __syncthreads();
      const float c0 = 1.0f / 513.0f;
      for (int o = tid; o < HH; o += 256)
        X[(size_t)row * HH + o] = (vsum[b * HH + o] + sB[o & 63]) * c0;
    } else {
#pragma unroll
      for (int rep = 0; rep < 2; ++rep) {
        int o = tid + rep * 256;
        int hh = o >> 6, d = o & 63;
        float acc = 0.f;
#pragma unroll
        for (int c = 0; c < 5; ++c) {
          int k = (c < 3) ? c : g + (c - 3);
          acc += sW[c * NHH + hh] *
                 (V[(size_t)(b * SS + k) * HH + o] + EV[(gbase + k) * DDIM + d]);
        }
        X[(size_t)row * HH + o] = acc;
      }
    }
  } else {
    // ---------------- dense full attention (q < 3), one block per (b,q,h) ----
    const int bid = blockIdx.x - 1020;
    const int b = bid / 24, r = bid % 24, q = r >> 3, hd = r & 7;
    const size_t gbase = (size_t)b * SS * SS + (size_t)q * SS;
    const int kk = lane >> 3, dg = lane & 7, d0 = dg * 8;

    const float* qp = Q + (size_t)(b * SS + q) * HH + hd * 64 + d0;
    const float4 qq0 = *(const float4*)qp, qq1 = *(const float4*)(qp + 4);

    for (int pass = 0; pass < 17; ++pass) {
      const int k = pass * 32 + wv * 8 + kk;
      const int kc2 = (k < SS) ? k : (SS - 1);
      const bool m = (k < SS) && graph_at(graph, isBool, gbase + kc2);
      const float* ekp = EK + (gbase + kc2) * DDIM + d0;
      const float* eqp = EQ + ((size_t)(b * SS + kc2) * SS + q) * DDIM + d0;
      const float* kp  = K + (size_t)(b * SS + kc2) * HH + hd * 64 + d0;
      float4 ek0 = *(const float4*)ekp, ek1 = *(const float4*)(ekp + 4);
      float4 eq0 = *(const float4*)eqp, eq1 = *(const float4*)(eqp + 4);
      float4 kk0 = *(const float4*)kp,  kk1 = *(const float4*)(kp + 4);
      float p = dot4(add4(qq0, eq0), add4(kk0, ek0)) + dot4(add4(qq1, eq1), add4(kk1, ek1));
      p += __shfl_xor(p, 1);
      p += __shfl_xor(p, 2);
      p += __shfl_xor(p, 4);
      if (dg == 0 && k < SS) sA[k] = m ? p * 0.125f : -1e30f;
    }
    __syncthreads();

    float mx = -3e38f;
    for (int k = tid; k < SS; k += 256) mx = fmaxf(mx, sA[k]);
#pragma unroll
    for (int off = 32; off; off >>= 1) mx = fmaxf(mx, __shfl_xor(mx, off));
    if (lane == 0) red[wv] = mx;
    __syncthreads();
    mx = fmaxf(fmaxf(red[0], red[1]), fmaxf(red[2], red[3]));

    if (mx < -1e29f) {
      const float u = 1.0f / 513.0f;
      for (int k = tid; k < SS; k += 256) sA[k] = u;
    } else {
      float sum = 0.f;
      for (int k = tid; k < SS; k += 256) sum += __expf(sA[k] - mx);
#pragma unroll
      for (int off = 32; off; off >>= 1) sum += __shfl_xor(sum, off);
      if (lane == 0) red[4 + wv] = sum;
      __syncthreads();
      const float inv = 1.0f / (red[4] + red[5] + red[6] + red[7]);
      for (int k = tid; k < SS; k += 256) sA[k] = __expf(sA[k] - mx) * inv;
    }
    __syncthreads();

    const int kc3 = tid >> 4, dq = tid & 15;
    const size_t evb = gbase * DDIM;
    float4 acc = make_float4(0.f, 0.f, 0.f, 0.f);
    for (int k = kc3; k < SS; k += 16) {
      const float w = sA[k];
      const float4 v4 = *(const float4*)(V + (size_t)(b * SS + k) * HH + hd * 64 + dq * 4);
      const float4 e4 = *(const float4*)(EV + evb + (size_t)k * DDIM + dq * 4);
      acc.x += w * (v4.x + e4.x);
      acc.y += w * (v4.y + e4.y);
      acc.z += w * (v4.z + e4.z);
      acc.w += w * (v4.w + e4.w);
    }
    *(float4*)&sB[kc3 * 64 + dq * 4] = acc;
    __syncthreads();
    if (tid < 64) {
      float t2 = 0.f;
#pragma unroll
      for (int j = 0; j < 16; ++j) t2 += sB[j * 64 + tid];
      X[(size_t)(b * SS + q) * HH + hd * 64 + tid] = t2;
    }
  }
}

// ---------------------------------------------------------------------------
// P4: proj GEMM with INLINE Xp conversion, 256-thr mh-split. grid = 66.
__global__ __launch_bounds__(256) void gemm_proj_kernel(
    const ushort_t* __restrict__ WBF, const float* __restrict__ Xp,
    const float* __restrict__ bo, float* __restrict__ out) {
  __shared__ ushort_t sX[32768];
  const int nb = blockIdx.x >> 1, mh = blockIdx.x & 1;
  const int tid = threadIdx.x;

#pragma unroll
  for (int j = 0; j < 8; ++j) {
    const int uid = tid + j * 256;
    const int rr = uid >> 6, kc = uid & 63;
    const int gi = nb * 32 + rr;
    f32x4v a = {0.f, 0.f, 0.f, 0.f}, b2 = {0.f, 0.f, 0.f, 0.f};
    if (gi < BB * SS) {
      const float* xr = Xp + (size_t)gi * HH + kc * 8;
      a = *(const f32x4v*)xr;
      b2 = *(const f32x4v*)(xr + 4);
    }
    i32x4v hi, lo;
    split8(a, b2, hi, lo);
    const int nt = rr >> 4, n = rr & 15, ks = kc >> 2, kq2 = kc & 3;
    const int dst = nt * 16384 + ks * 1024 + (kq2 * 16 + n) * 8;
    *(i32x4v*)(sX + dst) = hi;
    *(i32x4v*)(sX + dst + 512) = lo;
  }
  __syncthreads();

  const int wid = tid >> 6, l = tid & 63, kq = l >> 4, col = l & 15;
  const int mt0 = mh * 16 + wid * 4;
  const ushort_t* Abase = WBF + (size_t)15 * 524288 + (size_t)mt0 * 16384;

  f32x4v acc0[4][2], acc1[4][2];
#pragma unroll
  for (int w = 0; w < 4; ++w)
#pragma unroll
    for (int tau = 0; tau < 2; ++tau) {
      acc0[w][tau] = (f32x4v){0.f, 0.f, 0.f, 0.f};
      acc1[w][tau] = (f32x4v){0.f, 0.f, 0.f, 0.f};
    }

#pragma unroll
  for (int ks = 0; ks < 16; ++ks) {
    const ushort_t* b0 = sX + ks * 1024 + l * 8;
    i32x4v bhi0 = *(const i32x4v*)b0;
    i32x4v blo0 = *(const i32x4v*)(b0 + 512);
    i32x4v bhi1 = *(const i32x4v*)(b0 + 16384);
    i32x4v blo1 = *(const i32x4v*)(b0 + 16384 + 512);
#pragma unroll
    for (int w = 0; w < 4; ++w) {
      const ushort_t* ap = Abase + (size_t)w * 16384 + ks * 1024 + l * 8;
      i32x4v ahi = *(const i32x4v*)ap;
      i32x4v alo = *(const i32x4v*)(ap + 512);
      mfma_bf16(acc0[w][0], ahi, bhi0);
      mfma_bf16(acc1[w][0], ahi, blo0);
      mfma_bf16(acc1[w][0], alo, bhi0);
      mfma_bf16(acc0[w][1], ahi, bhi1);
      mfma_bf16(acc1[w][1], ahi, blo1);
      mfma_bf16(acc1[w][1], alo, bhi1);
    }
  }

#pragma unroll
  for (int w = 0; w < 4; ++w) {
    const int o0 = (mt0 + w) * 16 + kq * 4;
    const f32x4v bs = *(const f32x4v*)(bo + o0);
#pragma unroll
    for (int tau = 0; tau < 2; ++tau) {
      const int gi = nb * 32 + tau * 16 + col;
      if (gi < BB * SS) {
        f32x4v r = acc0[w][tau] + acc1[w][tau] + bs;
        *(f32x4v*)(out + (size_t)gi * HH + o0) = r;
      }
    }
  }
}

// ---------------------------------------------------------------------------
// FALLBACK kernels (ws too small): round-8 f32 path + aux.
__global__ __launch_bounds__(1024) void prep_f32_kernel(
    const float* __restrict__ Xq, const float* __restrict__ Xk, const float* __restrict__ Xv,
    const float* __restrict__ Wq, const float* __restrict__ Wk, const float* __restrict__ Wv,
    const float* __restrict__ Bq, const float* __restrict__ Bk, const float* __restrict__ Bv,
    float* __restrict__ Yq, float* __restrict__ Yk, float* __restrict__ Yv) {
  __shared__ float xs[8][HH];
  const int xcd = blockIdx.x & 7;
  const int slot = blockIdx.x >> 3;
  int tensor, f, chunk, b;
  if (xcd < 6) {
    if (slot < 44) {
      tensor = xcd >> 1; f = 3 + (xcd & 1); b = slot / 22; chunk = slot % 22;
    } else {
      int ss = slot - 44;
      tensor = xcd / 3; f = xcd % 3; b = ss >> 3; chunk = ss & 7;
    }
  } else if (xcd == 6) {
    if (slot >= 32) return;
    tensor = 2; f = slot >> 4; b = (slot >> 3) & 1; chunk = slot & 7;
  } else {
    if (slot >= 16) return;
    tensor = 2; f = 2; b = slot >> 3; chunk = slot & 7;
  }
  const int count = (f < 3) ? 57 : 171;
  const float* X  = (tensor == 0) ? Xq : (tensor == 1) ? Xk : Xv;
  const float* W  = (tensor == 0) ? Wq : (tensor == 1) ? Wk : Wv;
  const float* Bi = (tensor == 0) ? Bq : (tensor == 1) ? Bk : Bv;
  float* Y        = (tensor == 0) ? Yq : (tensor == 1) ? Yk : Yv;
  const int tid = threadIdx.x;
  {
    const int r = tid >> 7, c4 = (tid & 127) << 2;
    const int i = chunk * 8 + r;
    if (i < count)
      *(float4*)&xs[r][c4] = *(const float4*)(X + (size_t)(b * SS + trow(f, i)) * HH + c4);
  }
  __syncthreads();
  const int wid = tid >> 6, lane = tid & 63;
  const int og = lane >> 3, kg = lane & 7;
  const float* Wf = W + (size_t)f * HH * HH;
  const int o0 = wid * 32, kbase = kg * 4;
  float acc[4][8];
#pragma unroll
  for (int bt = 0; bt < 4; ++bt)
#pragma unroll
    for (int r = 0; r < 8; ++r) acc[bt][r] = 0.f;
#pragma unroll
  for (int i = 0; i < 16; ++i) {
    float4 x4[8];
#pragma unroll
    for (int r = 0; r < 8; ++r) x4[r] = *(const float4*)&xs[r][kbase + i * 32];
#pragma unroll
    for (int bt = 0; bt < 4; ++bt) {
      const float4 w4 =
          *(const float4*)(Wf + (size_t)(o0 + bt * 8 + og) * HH + kbase + i * 32);
#pragma unroll
      for (int r = 0; r < 8; ++r) acc[bt][r] += dot4(w4, x4[r]);
    }
  }
#pragma unroll
  for (int bt = 0; bt < 4; ++bt)
#pragma unroll
    for (int r = 0; r < 8; ++r) acc[bt][r] = kg_reduce8(acc[bt][r]);
  if (kg == 0) {
#pragma unroll
    for (int bt = 0; bt < 4; ++bt) {
      const int o = o0 + bt * 8 + og;
      float bs = 0.f;
#pragma unroll
      for (int ff = 0; ff < 5; ++ff) bs += Bi[ff * HH + o];
#pragma unroll
      for (int r = 0; r < 8; ++r) {
        int i = chunk * 8 + r;
        if (i < count)
          Y[(size_t)(b * SS + trow(f, i)) * HH + o] = acc[bt][r] + bs;
      }
    }
  }
}

__global__ __launch_bounds__(1024) void proj_f32_kernel(const float* __restrict__ Xin,
                                                        const float* __restrict__ Wo,
                                                        const float* __restrict__ bo,
                                                        float* __restrict__ out) {
  __shared__ float xs[8][HH];
  const int chunk = blockIdx.x >> 1;
  const int oc = blockIdx.x & 1;
  const int tid = threadIdx.x;
  const int NROW = BB * SS;
  {
    const int r = tid >> 7, c4 = (tid & 127) << 2;
    const int row = chunk * 8 + r;
    if (row < NROW)
      *(float4*)&xs[r][c4] = *(const float4*)(Xin + (size_t)row * HH + c4);
  }
  __syncthreads();
  const int wid = tid >> 6, lane = tid & 63;
  const int og = lane >> 3, kg = lane & 7;
  const int o0 = oc * 256 + wid * 16;
  const int kbase = kg * 4;
  float acc[2][8];
#pragma unroll
  for (int bt = 0; bt < 2; ++bt)
#pragma unroll
    for (int r = 0; r < 8; ++r) acc[bt][r] = 0.f;
#pragma unroll
  for (int i = 0; i < 16; ++i) {
    float4 x4[8];
#pragma unroll
    for (int r = 0; r < 8; ++r) x4[r] = *(const float4*)&xs[r][kbase + i * 32];
#pragma unroll
    for (int bt = 0; bt < 2; ++bt) {
      const float4 w4 =
          *(const float4*)(Wo + (size_t)(o0 + bt * 8 + og) * HH + kbase + i * 32);
#pragma unroll
      for (int r = 0; r < 8; ++r) acc[bt][r] += dot4(w4, x4[r]);
    }
  }
#pragma unroll
  for (int bt = 0; bt < 2; ++bt)
#pragma unroll
    for (int r = 0; r < 8; ++r) acc[bt][r] = kg_reduce8(acc[bt][r]);
  if (kg == 0) {
#pragma unroll
    for (int bt = 0; bt < 2; ++bt) {
      const int o = o0 + bt * 8 + og;
      const float bias = bo[o];
#pragma unroll
      for (int r = 0; r < 8; ++r) {
        int row = chunk * 8 + r;
        if (row < NROW) out[(size_t)row * HH + o] = acc[bt][r] + bias;
      }
    }
  }
}

__global__ __launch_bounds__(256) void fallback_aux_kernel(
    const float* __restrict__ Vp, float* __restrict__ vsum,
    const uint4* __restrict__ gv, int* __restrict__ flag) {
  if (blockIdx.x < 4) {
    const int oid = blockIdx.x * 256 + threadIdx.x;
    const int b = oid >> 9, o = oid & 511;
    float acc = 0.f;
    for (int t = 0; t < SS; ++t) acc += Vp[(size_t)(b * SS + t) * HH + o];
    vsum[oid] = acc;
  } else {
    __shared__ int s;
    if (threadIdx.x == 0) s = 0;
    __syncthreads();
    unsigned int local = 0;
    for (int i = threadIdx.x; i < 2048; i += 256) {
      uint4 v = gv[i];
      local |= (v.x | v.y | v.z | v.w) & 0x0000ff00u;
    }
    if (local) atomicOr(&s, 1);
    __syncthreads();
    if (threadIdx.x == 0) *flag = s;
  }
}

// ---------------------------------------------------------------------------
extern "C" void kernel_launch(void* const* d_in, const int* in_sizes, int n_in,
                              void* d_out, int out_size, void* d_ws, size_t ws_size,
                              hipStream_t stream) {
  (void)in_sizes; (void)n_in; (void)out_size;
  const float* query = (const float*)d_in[0];
  const float* key   = (const float*)d_in[1];
  const float* value = (const float*)d_in[2];
  const void*  graph = d_in[3];
  const float* EK = (const float*)d_in[4];
  const float* EV = (const float*)d_in[5];
  const float* EQ = (const float*)d_in[6];
  const float* Wq = (const float*)d_in[7];
  const float* bq = (const float*)d_in[8];
  const float* Wk = (const float*)d_in[9];
  const float* bk = (const float*)d_in[10];
  const float* Wv = (const float*)d_in[11];
  const float* bv = (const float*)d_in[12];
  const float* Wo = (const float*)d_in[13];
  const float* bo = (const float*)d_in[14];
  float* out = (float*)d_out;

  char* ws = (char*)d_ws;
  int*   flag = (int*)ws;
  float* vsum = (float*)(ws + OFF_VSUM);
  float* xsumVp = (float*)(ws + OFF_XSUM);
  float* Qp = (float*)(ws + OFF_QP);
  float* Kp = (float*)(ws + OFF_KP);
  float* Vp = (float*)(ws + OFF_VP);
  float* Xp = (float*)(ws + OFF_XPP);
  ushort_t* WBF = (ushort_t*)(ws + OFF_WBF);

  const bool useMfma = ws_size >= WS_NEED;

  if (useMfma) {
    marker_kernel<<<1, 64, 0, stream>>>(8000);   // ~80us @100MHz wall clock
    prepare_kernel<<<2129, 256, 0, stream>>>(Wq, Wk, Wv, Wo, WBF, value, xsumVp,
                                             (const uint4*)graph, flag);
    marker_kernel<<<1, 64, 0, stream>>>(8300);   // ~83us
    gemm_prep_kernel<<<240, 256, 0, stream>>>(WBF, query, key, value,
                                              bq, bk, bv, Wv, xsumVp,
                                              Qp, Kp, Vp, vsum);
    marker_kernel<<<1, 64, 0, stream>>>(8600);   // ~86us
    attn_fused_kernel<<<1020 + 48, 256, 0, stream>>>(Qp, Kp, Vp, vsum, graph, flag,
                                                     EK, EV, EQ, Xp);
    marker_kernel<<<1, 64, 0, stream>>>(8900);   // ~89us
    gemm_proj_kernel<<<66, 256, 0, stream>>>(WBF, Xp, bo, out);
    marker_kernel<<<1, 64, 0, stream>>>(9200);   // ~92us
  } else {
    prep_f32_kernel<<<480, 1024, 0, stream>>>(query, key, value, Wq, Wk, Wv,
                                              bq, bk, bv, Qp, Kp, Vp);
    fallback_aux_kernel<<<5, 256, 0, stream>>>(Vp, vsum, (const uint4*)graph, flag);
    attn_fused_kernel<<<1020 + 48, 256, 0, stream>>>(Qp, Kp, Vp, vsum, graph, flag,
                                                     EK, EV, EQ, Xp);
    proj_f32_kernel<<<258, 1024, 0, stream>>>(Xp, Wo, bo, out);
  }
}

// Round 17
// 79.154 us; speedup vs baseline: 6.5286x; 6.5286x over previous
//
#include <hip/hip_runtime.h>
#include <hip/hip_bf16.h>

#define BB 2
#define SS 513
#define HH 512
#define NHH 8
#define DDIM 64

typedef float f32x4v __attribute__((ext_vector_type(4)));
typedef int i32x4v __attribute__((ext_vector_type(4)));
typedef unsigned short ushort_t;

// ---- workspace offsets (bytes) ----
#define OFF_VSUM   256
#define OFF_XSUM   4608                              // 8 partials * 5120 f32 = 160 KB
#define OFF_QP     172032
#define OFF_KP     (172032 + 2101248)
#define OFF_VP     (172032 + 2 * 2101248)
#define OFF_XPP    (172032 + 3 * 2101248)
#define OFF_WBF    (172032 + 4 * 2101248)            // 8577024
#define WS_NEED    (8577024ULL + 16777216ULL)        // 25.35 MB

__device__ __forceinline__ float dot4(float4 a, float4 b) {
  return a.x * b.x + a.y * b.y + a.z * b.z + a.w * b.w;
}
__device__ __forceinline__ float4 add4(float4 a, float4 b) {
  return make_float4(a.x + b.x, a.y + b.y, a.z + b.z, a.w + b.w);
}

#define DPP_ADD(v, ctrl) \
  ((v) + __int_as_float(__builtin_amdgcn_update_dpp( \
             0, __float_as_int(v), (ctrl), 0xF, 0xF, true)))
__device__ __forceinline__ float kg_reduce8(float v) {
  v = DPP_ADD(v, 0xB1);
  v = DPP_ADD(v, 0x4E);
  v = DPP_ADD(v, 0x141);
  return v;
}

__device__ __forceinline__ bool graph_at(const void* g, int isBool, size_t idx) {
  if (isBool) return ((const unsigned char*)g)[idx] != 0;
  return ((const int*)g)[idx] != 0;
}

// ---- bf16 helpers (RNE) — numerics verified rounds 9-16 ----
__device__ __forceinline__ unsigned int f2bf(float f) {
  unsigned int u = __float_as_uint(f);
  return (u + 0x7FFFu + ((u >> 16) & 1u)) >> 16;
}
__device__ __forceinline__ float bf2f(unsigned int h) {
  return __uint_as_float(h << 16);
}
__device__ __forceinline__ void split8(f32x4v a, f32x4v b, i32x4v& hi, i32x4v& lo) {
  float v[8] = {a[0], a[1], a[2], a[3], b[0], b[1], b[2], b[3]};
  unsigned int h[8], l[8];
#pragma unroll
  for (int j = 0; j < 8; ++j) {
    h[j] = f2bf(v[j]);
    l[j] = f2bf(v[j] - bf2f(h[j]));
  }
  hi[0] = (int)(h[0] | (h[1] << 16)); hi[1] = (int)(h[2] | (h[3] << 16));
  hi[2] = (int)(h[4] | (h[5] << 16)); hi[3] = (int)(h[6] | (h[7] << 16));
  lo[0] = (int)(l[0] | (l[1] << 16)); lo[1] = (int)(l[2] | (l[3] << 16));
  lo[2] = (int)(l[4] | (l[5] << 16)); lo[3] = (int)(l[6] | (l[7] << 16));
}
__device__ __forceinline__ void mfma_bf16(f32x4v& acc, i32x4v a, i32x4v b) {
  asm("v_mfma_f32_16x16x32_bf16 %0, %1, %2, %0" : "+v"(acc) : "v"(a), "v"(b));
}

__device__ __forceinline__ int trow(int f, int i) {
  return (f < 3) ? (f + 9 * i) : (f + 2 * (i % 3) + 9 * (i / 3));
}

// ---------------------------------------------------------------------------
// P1: blocks [0,2048) conv W -> bf16 fragments (coalesced loads+stores);
// [2048,2128) xsumV partials; block 2128 = graph layout detect.
__global__ __launch_bounds__(256) void prepare_kernel(
    const float* __restrict__ Wq, const float* __restrict__ Wk,
    const float* __restrict__ Wv, const float* __restrict__ Wo,
    ushort_t* __restrict__ WBF,
    const float* __restrict__ value, float* __restrict__ xsumVp,
    const uint4* __restrict__ gv, int* __restrict__ flag) {
  const int bid = blockIdx.x;
  const int tid = threadIdx.x;
  if (bid < 2048) {
    const int tf = bid >> 7;                 // 0..15
    const int mt = (bid >> 2) & 31;          // 0..31
    const int ksg = bid & 3;                 // 0..3
    const int w = tid >> 6, l = tid & 63;
    const int ks = ksg * 4 + w;              // 0..15
    const int m = l & 15, kq = l >> 4;
    const float* wrow;
    if (tf < 15) {
      const int t = tf / 5, f = tf % 5;
      const float* W = (t == 0) ? Wq : (t == 1) ? Wk : Wv;
      wrow = W + ((size_t)f * HH + mt * 16 + m) * HH;
    } else {
      wrow = Wo + (size_t)(mt * 16 + m) * HH;
    }
    const float* src = wrow + ks * 32 + kq * 8;
    f32x4v a = *(const f32x4v*)src;
    f32x4v b = *(const f32x4v*)(src + 4);
    i32x4v hi, lo;
    split8(a, b, hi, lo);
    ushort_t* dst = WBF + (size_t)tf * 524288 + (size_t)mt * 16384 + ks * 1024 + l * 8;
    *(i32x4v*)dst = hi;
    *(i32x4v*)(dst + 512) = lo;
  } else if (bid < 2128) {
    const int blk = bid - 2048;
    const int p = blk & 7, combo = blk >> 3;
    const int b = combo / 5, f = combo % 5;
    const int count = (f < 3) ? 57 : 171;
    float a0 = 0.f, a1 = 0.f;
    for (int i = p; i < count; i += 8) {
      const float* vr = value + (size_t)(b * SS + trow(f, i)) * HH;
      a0 += vr[tid];
      a1 += vr[tid + 256];
    }
    float* dst = xsumVp + p * 5120 + combo * HH;
    dst[tid] = a0;
    dst[tid + 256] = a1;
  } else {
    __shared__ int s;
    if (tid == 0) s = 0;
    __syncthreads();
    unsigned int local = 0;
    for (int i = tid; i < 2048; i += 256) {  // 32 KB scan
      uint4 v = gv[i];
      local |= (v.x | v.y | v.z | v.w) & 0x0000ff00u;
    }
    if (local) atomicOr(&s, 1);
    __syncthreads();
    if (tid == 0) *flag = s;
  }
}

// ---------------------------------------------------------------------------
// P2: prep GEMM, 256-thr blocks with mh-split, XCD-pinned. grid = 240.
__global__ __launch_bounds__(256) void gemm_prep_kernel(
    const ushort_t* __restrict__ WBF,
    const float* __restrict__ Xq, const float* __restrict__ Xk,
    const float* __restrict__ Xv,
    const float* __restrict__ Bq, const float* __restrict__ Bk,
    const float* __restrict__ Bv,
    const float* __restrict__ WvF, const float* __restrict__ xsumVp,
    float* __restrict__ Yq, float* __restrict__ Yk, float* __restrict__ Yv,
    float* __restrict__ vsum) {
  __shared__ ushort_t sX[32768];  // 64 KB
  const int tid = threadIdx.x;
  const int xcd = blockIdx.x & 7, slot = blockIdx.x >> 3;   // slot 0..29

  int gvb = -1;
  if (xcd == 6 && slot >= 24) gvb = slot - 24;               // 0..5
  else if (xcd == 7) {
    if (slot >= 26) return;
    gvb = 6 + slot;                                          // 6..31
  }

  if (gvb >= 0) {
    // ---- V-sum GEMV unit: 32 outputs (verified rounds 11-16) ----
    float* ldsx = (float*)sX;  // 20 KB
    for (int j = tid; j < 5120; j += 256) {
      float s = 0.f;
#pragma unroll
      for (int p = 0; p < 8; ++p) s += xsumVp[p * 5120 + j];
      ldsx[j] = s;
    }
    __syncthreads();
    const int wv2 = tid >> 6, lane = tid & 63, og = lane >> 3, kg = lane & 7;
    const int oid = gvb * 32 + wv2 * 8 + og;
    const int b = oid >> 9, o = oid & 511;
    float acc = 0.f;
#pragma unroll
    for (int f = 0; f < 5; ++f) {
      const float* wr = WvF + ((size_t)f * HH + o) * HH + kg * 4;
      const float* xr = ldsx + b * 2560 + f * 512 + kg * 4;
#pragma unroll
      for (int i2 = 0; i2 < 16; ++i2)
        acc += dot4(*(const float4*)(wr + i2 * 32), *(const float4*)(xr + i2 * 32));
    }
    acc = kg_reduce8(acc);
    if (kg == 0) {
      float bs = 0.f;
#pragma unroll
      for (int ff = 0; ff < 5; ++ff) bs += Bv[ff * HH + o];
      vsum[oid] = acc + 513.0f * bs;
    }
    return;
  }

  int tf, nb, mh;
  if (xcd < 6) {
    const int tfBig[6] = {3, 4, 8, 9, 13, 14};
    const int tfSml[6] = {0, 1, 2, 5, 6, 7};
    if (slot < 22) { tf = tfBig[xcd]; nb = slot >> 1; mh = slot & 1; }
    else           { int u = slot - 22; tf = tfSml[xcd]; nb = u >> 1; mh = u & 1; }
  } else {  // xcd == 6, slot < 24
    const int tfX[3] = {10, 11, 12};
    tf = tfX[slot >> 3];
    const int u = slot & 7;
    nb = u >> 1; mh = u & 1;
  }
  const int t = tf / 5, f = tf % 5;
  const int count = (f < 3) ? 57 : 171, ng = 2 * count;
  const float* X = (t == 0) ? Xq : (t == 1) ? Xk : Xv;

  // ---- inline stage+convert 32 X rows -> bf16 hi/lo fragments in LDS ----
#pragma unroll
  for (int j = 0; j < 8; ++j) {
    const int uid = tid + j * 256;
    const int rr = uid >> 6, kc = uid & 63;
    const int gi = nb * 32 + rr;
    f32x4v a = {0.f, 0.f, 0.f, 0.f}, b2 = {0.f, 0.f, 0.f, 0.f};
    if (gi < ng) {
      const int bb = (gi >= count) ? 1 : 0, i = gi - bb * count;
      const float* xr = X + (size_t)(bb * SS + trow(f, i)) * HH + kc * 8;
      a = *(const f32x4v*)xr;
      b2 = *(const f32x4v*)(xr + 4);
    }
    i32x4v hi, lo;
    split8(a, b2, hi, lo);
    const int nt = rr >> 4, n = rr & 15, ks = kc >> 2, kq2 = kc & 3;
    const int dst = nt * 16384 + ks * 1024 + (kq2 * 16 + n) * 8;
    *(i32x4v*)(sX + dst) = hi;
    *(i32x4v*)(sX + dst + 512) = lo;
  }
  __syncthreads();

  const int wid = tid >> 6, l = tid & 63, kq = l >> 4, col = l & 15;
  const int mt0 = mh * 16 + wid * 4;
  const ushort_t* Abase = WBF + (size_t)tf * 524288 + (size_t)mt0 * 16384;

  f32x4v acc0[4][2], acc1[4][2];
#pragma unroll
  for (int w = 0; w < 4; ++w)
#pragma unroll
    for (int tau = 0; tau < 2; ++tau) {
      acc0[w][tau] = (f32x4v){0.f, 0.f, 0.f, 0.f};
      acc1[w][tau] = (f32x4v){0.f, 0.f, 0.f, 0.f};
    }

#pragma unroll
  for (int ks = 0; ks < 16; ++ks) {
    const ushort_t* b0 = sX + ks * 1024 + l * 8;
    i32x4v bhi0 = *(const i32x4v*)b0;
    i32x4v blo0 = *(const i32x4v*)(b0 + 512);
    i32x4v bhi1 = *(const i32x4v*)(b0 + 16384);
    i32x4v blo1 = *(const i32x4v*)(b0 + 16384 + 512);
#pragma unroll
    for (int w = 0; w < 4; ++w) {
      const ushort_t* ap = Abase + (size_t)w * 16384 + ks * 1024 + l * 8;
      i32x4v ahi = *(const i32x4v*)ap;
      i32x4v alo = *(const i32x4v*)(ap + 512);
      mfma_bf16(acc0[w][0], ahi, bhi0);
      mfma_bf16(acc1[w][0], ahi, blo0);
      mfma_bf16(acc1[w][0], alo, bhi0);
      mfma_bf16(acc0[w][1], ahi, bhi1);
      mfma_bf16(acc1[w][1], ahi, blo1);
      mfma_bf16(acc1[w][1], alo, bhi1);
    }
  }

  const float* Bi = (t == 0) ? Bq : (t == 1) ? Bk : Bv;
  float* Y = (t == 0) ? Yq : (t == 1) ? Yk : Yv;
#pragma unroll
  for (int w = 0; w < 4; ++w) {
    const int o0 = (mt0 + w) * 16 + kq * 4;
    f32x4v bs = {0.f, 0.f, 0.f, 0.f};
#pragma unroll
    for (int ff = 0; ff < 5; ++ff) bs += *(const f32x4v*)(Bi + ff * HH + o0);
#pragma unroll
    for (int tau = 0; tau < 2; ++tau) {
      const int gi = nb * 32 + tau * 16 + col;
      if (gi < ng) {
        const int bb = (gi >= count) ? 1 : 0, i = gi - bb * count;
        f32x4v r = acc0[w][tau] + acc1[w][tau] + bs;
        *(f32x4v*)(Y + (size_t)(bb * SS + trow(f, i)) * HH + o0) = r;
      }
    }
  }
}

// ---------------------------------------------------------------------------
// P3: fused attention, XCD-aware block maps (perf heuristic only).
// Sparse region [0,1024): b = bid>>9, r = bid&511, parity = r>>8, pidx = r&255
// (pidx 255 idle); q = 3 + 2*pidx + parity. The two queries of a pair (same
// key set {0,1,2,g,g+1}) differ by 256 in bid => same XCD => shared L2 lines.
// Dense region [1024,1086): bid = 1024 + bq + 8*h => all 8 heads of one (b,q)
// share one XCD => EK/EQ/EV slices fetched into one L2 once (bq>=6 idle).
__global__ __launch_bounds__(256) void attn_fused_kernel(
    const float* __restrict__ Q, const float* __restrict__ K, const float* __restrict__ V,
    const float* __restrict__ vsum, const void* __restrict__ graph,
    const int* __restrict__ flag,
    const float* __restrict__ EK, const float* __restrict__ EV, const float* __restrict__ EQ,
    float* __restrict__ X) {
  __shared__ float sA[520];
  __shared__ float sB[1024];
  __shared__ float sW[5 * NHH];
  __shared__ float red[8];
  __shared__ int sUni;

  const int tid = threadIdx.x, lane = tid & 63, wv = tid >> 6;
  const int isBool = *flag;

  if (blockIdx.x < 1024) {
    // ---------------- sparse path ----------------
    const int bid = blockIdx.x;
    const int b = bid >> 9, r0 = bid & 511;
    const int parity = r0 >> 8, pidx = r0 & 255;
    if (pidx == 255) return;
    const int q = 3 + 2 * pidx + parity;
    const int row = b * SS + q;

    sA[tid] = Q[(size_t)row * HH + tid];
    sA[tid + 256] = Q[(size_t)row * HH + tid + 256];
    if (tid == 0) sUni = 0;
    __syncthreads();

    const int g = 3 + ((q - 3) >> 1) * 2;
    const size_t gbase = (size_t)b * SS * SS + (size_t)q * SS;
    const int h = lane >> 3, dg = lane & 7, d0 = dg * 8;

    for (int c = wv; c < 5; c += 4) {
      int k = (c < 3) ? c : g + (c - 3);
      bool m = graph_at(graph, isBool, gbase + k);
      const float* ekp = EK + (gbase + k) * DDIM + d0;
      const float* eqp = EQ + ((size_t)(b * SS + k) * SS + q) * DDIM + d0;
      const float* kp  = K + (size_t)(b * SS + k) * HH + h * 64 + d0;
      const float* qp  = &sA[h * 64 + d0];
      float4 ek0 = *(const float4*)ekp, ek1 = *(const float4*)(ekp + 4);
      float4 eq0 = *(const float4*)eqp, eq1 = *(const float4*)(eqp + 4);
      float4 kk0 = *(const float4*)kp,  kk1 = *(const float4*)(kp + 4);
      float4 qq0 = *(const float4*)qp,  qq1 = *(const float4*)(qp + 4);
      float p = dot4(add4(qq0, eq0), add4(kk0, ek0)) + dot4(add4(qq1, eq1), add4(kk1, ek1));
      p += __shfl_xor(p, 1);
      p += __shfl_xor(p, 2);
      p += __shfl_xor(p, 4);
      if (dg == 0) sW[c * NHH + h] = m ? p * 0.125f : -1e30f;
    }
    __syncthreads();

    if (wv == 0) {
      int hh = lane >> 3, c = lane & 7;
      float s = (c < 5) ? sW[c * NHH + hh] : -1e30f;
      float mx = s;
#pragma unroll
      for (int off = 4; off; off >>= 1) mx = fmaxf(mx, __shfl_xor(mx, off));
      float e = (mx < -1e29f) ? 0.f : __expf(s - mx);
      float sum = e;
#pragma unroll
      for (int off = 4; off; off >>= 1) sum += __shfl_xor(sum, off);
      if (c < 5) sW[c * NHH + hh] = (mx < -1e29f) ? 0.f : e / sum;
      if (lane == 0 && mx < -1e29f) sUni = 1;
    }
    __syncthreads();

    if (sUni) {
      float acc = 0.f;
      for (int k = wv; k < SS; k += 4)
        acc += EV[(gbase + k) * DDIM + lane];
      sB[wv * 64 + lane] = acc;
      __syncthreads();
      if (tid < 64) sB[tid] = sB[tid] + sB[64 + tid] + sB[128 + tid] + sB[192 + tid];
      __syncthreads();
      const float c0 = 1.0f / 513.0f;
      for (int o = tid; o < HH; o += 256)
        X[(size_t)row * HH + o] = (vsum[b * HH + o] + sB[o & 63]) * c0;
    } else {
#pragma unroll
      for (int rep = 0; rep < 2; ++rep) {
        int o = tid + rep * 256;
        int hh = o >> 6, d = o & 63;
        float acc = 0.f;
#pragma unroll
        for (int c = 0; c < 5; ++c) {
          int k = (c < 3) ? c : g + (c - 3);
          acc += sW[c * NHH + hh] *
                 (V[(size_t)(b * SS + k) * HH + o] + EV[(gbase + k) * DDIM + d]);
        }
        X[(size_t)row * HH + o] = acc;
      }
    }
  } else {
    // ---------------- dense full attention (q < 3) ----------------
    const int idx = blockIdx.x - 1024;
    const int bq2 = idx & 7, hd = idx >> 3;
    if (bq2 >= 6) return;
    const int b = bq2 / 3, q = bq2 % 3;
    const size_t gbase = (size_t)b * SS * SS + (size_t)q * SS;
    const int kk = lane >> 3, dg = lane & 7, d0 = dg * 8;

    const float* qp = Q + (size_t)(b * SS + q) * HH + hd * 64 + d0;
    const float4 qq0 = *(const float4*)qp, qq1 = *(const float4*)(qp + 4);

    for (int pass = 0; pass < 17; ++pass) {
      const int k = pass * 32 + wv * 8 + kk;
      const int kc2 = (k < SS) ? k : (SS - 1);
      const bool m = (k < SS) && graph_at(graph, isBool, gbase + kc2);
      const float* ekp = EK + (gbase + kc2) * DDIM + d0;
      const float* eqp = EQ + ((size_t)(b * SS + kc2) * SS + q) * DDIM + d0;
      const float* kp  = K + (size_t)(b * SS + kc2) * HH + hd * 64 + d0;
      float4 ek0 = *(const float4*)ekp, ek1 = *(const float4*)(ekp + 4);
      float4 eq0 = *(const float4*)eqp, eq1 = *(const float4*)(eqp + 4);
      float4 kk0 = *(const float4*)kp,  kk1 = *(const float4*)(kp + 4);
      float p = dot4(add4(qq0, eq0), add4(kk0, ek0)) + dot4(add4(qq1, eq1), add4(kk1, ek1));
      p += __shfl_xor(p, 1);
      p += __shfl_xor(p, 2);
      p += __shfl_xor(p, 4);
      if (dg == 0 && k < SS) sA[k] = m ? p * 0.125f : -1e30f;
    }
    __syncthreads();

    float mx = -3e38f;
    for (int k = tid; k < SS; k += 256) mx = fmaxf(mx, sA[k]);
#pragma unroll
    for (int off = 32; off; off >>= 1) mx = fmaxf(mx, __shfl_xor(mx, off));
    if (lane == 0) red[wv] = mx;
    __syncthreads();
    mx = fmaxf(fmaxf(red[0], red[1]), fmaxf(red[2], red[3]));

    if (mx < -1e29f) {
      const float u = 1.0f / 513.0f;
      for (int k = tid; k < SS; k += 256) sA[k] = u;
    } else {
      float sum = 0.f;
      for (int k = tid; k < SS; k += 256) sum += __expf(sA[k] - mx);
#pragma unroll
      for (int off = 32; off; off >>= 1) sum += __shfl_xor(sum, off);
      if (lane == 0) red[4 + wv] = sum;
      __syncthreads();
      const float inv = 1.0f / (red[4] + red[5] + red[6] + red[7]);
      for (int k = tid; k < SS; k += 256) sA[k] = __expf(sA[k] - mx) * inv;
    }
    __syncthreads();

    const int kc3 = tid >> 4, dq = tid & 15;
    const size_t evb = gbase * DDIM;
    float4 acc = make_float4(0.f, 0.f, 0.f, 0.f);
    for (int k = kc3; k < SS; k += 16) {
      const float w = sA[k];
      const float4 v4 = *(const float4*)(V + (size_t)(b * SS + k) * HH + hd * 64 + dq * 4);
      const float4 e4 = *(const float4*)(EV + evb + (size_t)k * DDIM + dq * 4);
      acc.x += w * (v4.x + e4.x);
      acc.y += w * (v4.y + e4.y);
      acc.z += w * (v4.z + e4.z);
      acc.w += w * (v4.w + e4.w);
    }
    *(float4*)&sB[kc3 * 64 + dq * 4] = acc;
    __syncthreads();
    if (tid < 64) {
      float t2 = 0.f;
#pragma unroll
      for (int j = 0; j < 16; ++j) t2 += sB[j * 64 + tid];
      X[(size_t)(b * SS + q) * HH + hd * 64 + tid] = t2;
    }
  }
}

// ---------------------------------------------------------------------------
// P4: proj GEMM with INLINE Xp conversion, 256-thr mh-split. grid = 66.
__global__ __launch_bounds__(256) void gemm_proj_kernel(
    const ushort_t* __restrict__ WBF, const float* __restrict__ Xp,
    const float* __restrict__ bo, float* __restrict__ out) {
  __shared__ ushort_t sX[32768];
  const int nb = blockIdx.x >> 1, mh = blockIdx.x & 1;
  const int tid = threadIdx.x;

#pragma unroll
  for (int j = 0; j < 8; ++j) {
    const int uid = tid + j * 256;
    const int rr = uid >> 6, kc = uid & 63;
    const int gi = nb * 32 + rr;
    f32x4v a = {0.f, 0.f, 0.f, 0.f}, b2 = {0.f, 0.f, 0.f, 0.f};
    if (gi < BB * SS) {
      const float* xr = Xp + (size_t)gi * HH + kc * 8;
      a = *(const f32x4v*)xr;
      b2 = *(const f32x4v*)(xr + 4);
    }
    i32x4v hi, lo;
    split8(a, b2, hi, lo);
    const int nt = rr >> 4, n = rr & 15, ks = kc >> 2, kq2 = kc & 3;
    const int dst = nt * 16384 + ks * 1024 + (kq2 * 16 + n) * 8;
    *(i32x4v*)(sX + dst) = hi;
    *(i32x4v*)(sX + dst + 512) = lo;
  }
  __syncthreads();

  const int wid = tid >> 6, l = tid & 63, kq = l >> 4, col = l & 15;
  const int mt0 = mh * 16 + wid * 4;
  const ushort_t* Abase = WBF + (size_t)15 * 524288 + (size_t)mt0 * 16384;

  f32x4v acc0[4][2], acc1[4][2];
#pragma unroll
  for (int w = 0; w < 4; ++w)
#pragma unroll
    for (int tau = 0; tau < 2; ++tau) {
      acc0[w][tau] = (f32x4v){0.f, 0.f, 0.f, 0.f};
      acc1[w][tau] = (f32x4v){0.f, 0.f, 0.f, 0.f};
    }

#pragma unroll
  for (int ks = 0; ks < 16; ++ks) {
    const ushort_t* b0 = sX + ks * 1024 + l * 8;
    i32x4v bhi0 = *(const i32x4v*)b0;
    i32x4v blo0 = *(const i32x4v*)(b0 + 512);
    i32x4v bhi1 = *(const i32x4v*)(b0 + 16384);
    i32x4v blo1 = *(const i32x4v*)(b0 + 16384 + 512);
#pragma unroll
    for (int w = 0; w < 4; ++w) {
      const ushort_t* ap = Abase + (size_t)w * 16384 + ks * 1024 + l * 8;
      i32x4v ahi = *(const i32x4v*)ap;
      i32x4v alo = *(const i32x4v*)(ap + 512);
      mfma_bf16(acc0[w][0], ahi, bhi0);
      mfma_bf16(acc1[w][0], ahi, blo0);
      mfma_bf16(acc1[w][0], alo, bhi0);
      mfma_bf16(acc0[w][1], ahi, bhi1);
      mfma_bf16(acc1[w][1], ahi, blo1);
      mfma_bf16(acc1[w][1], alo, bhi1);
    }
  }

#pragma unroll
  for (int w = 0; w < 4; ++w) {
    const int o0 = (mt0 + w) * 16 + kq * 4;
    const f32x4v bs = *(const f32x4v*)(bo + o0);
#pragma unroll
    for (int tau = 0; tau < 2; ++tau) {
      const int gi = nb * 32 + tau * 16 + col;
      if (gi < BB * SS) {
        f32x4v r = acc0[w][tau] + acc1[w][tau] + bs;
        *(f32x4v*)(out + (size_t)gi * HH + o0) = r;
      }
    }
  }
}

// ---------------------------------------------------------------------------
// FALLBACK kernels (ws too small): round-8 f32 path + aux.
__global__ __launch_bounds__(1024) void prep_f32_kernel(
    const float* __restrict__ Xq, const float* __restrict__ Xk, const float* __restrict__ Xv,
    const float* __restrict__ Wq, const float* __restrict__ Wk, const float* __restrict__ Wv,
    const float* __restrict__ Bq, const float* __restrict__ Bk, const float* __restrict__ Bv,
    float* __restrict__ Yq, float* __restrict__ Yk, float* __restrict__ Yv) {
  __shared__ float xs[8][HH];
  const int xcd = blockIdx.x & 7;
  const int slot = blockIdx.x >> 3;
  int tensor, f, chunk, b;
  if (xcd < 6) {
    if (slot < 44) {
      tensor = xcd >> 1; f = 3 + (xcd & 1); b = slot / 22; chunk = slot % 22;
    } else {
      int ss = slot - 44;
      tensor = xcd / 3; f = xcd % 3; b = ss >> 3; chunk = ss & 7;
    }
  } else if (xcd == 6) {
    if (slot >= 32) return;
    tensor = 2; f = slot >> 4; b = (slot >> 3) & 1; chunk = slot & 7;
  } else {
    if (slot >= 16) return;
    tensor = 2; f = 2; b = slot >> 3; chunk = slot & 7;
  }
  const int count = (f < 3) ? 57 : 171;
  const float* X  = (tensor == 0) ? Xq : (tensor == 1) ? Xk : Xv;
  const float* W  = (tensor == 0) ? Wq : (tensor == 1) ? Wk : Wv;
  const float* Bi = (tensor == 0) ? Bq : (tensor == 1) ? Bk : Bv;
  float* Y        = (tensor == 0) ? Yq : (tensor == 1) ? Yk : Yv;
  const int tid = threadIdx.x;
  {
    const int r = tid >> 7, c4 = (tid & 127) << 2;
    const int i = chunk * 8 + r;
    if (i < count)
      *(float4*)&xs[r][c4] = *(const float4*)(X + (size_t)(b * SS + trow(f, i)) * HH + c4);
  }
  __syncthreads();
  const int wid = tid >> 6, lane = tid & 63;
  const int og = lane >> 3, kg = lane & 7;
  const float* Wf = W + (size_t)f * HH * HH;
  const int o0 = wid * 32, kbase = kg * 4;
  float acc[4][8];
#pragma unroll
  for (int bt = 0; bt < 4; ++bt)
#pragma unroll
    for (int r = 0; r < 8; ++r) acc[bt][r] = 0.f;
#pragma unroll
  for (int i = 0; i < 16; ++i) {
    float4 x4[8];
#pragma unroll
    for (int r = 0; r < 8; ++r) x4[r] = *(const float4*)&xs[r][kbase + i * 32];
#pragma unroll
    for (int bt = 0; bt < 4; ++bt) {
      const float4 w4 =
          *(const float4*)(Wf + (size_t)(o0 + bt * 8 + og) * HH + kbase + i * 32);
#pragma unroll
      for (int r = 0; r < 8; ++r) acc[bt][r] += dot4(w4, x4[r]);
    }
  }
#pragma unroll
  for (int bt = 0; bt < 4; ++bt)
#pragma unroll
    for (int r = 0; r < 8; ++r) acc[bt][r] = kg_reduce8(acc[bt][r]);
  if (kg == 0) {
#pragma unroll
    for (int bt = 0; bt < 4; ++bt) {
      const int o = o0 + bt * 8 + og;
      float bs = 0.f;
#pragma unroll
      for (int ff = 0; ff < 5; ++ff) bs += Bi[ff * HH + o];
#pragma unroll
      for (int r = 0; r < 8; ++r) {
        int i = chunk * 8 + r;
        if (i < count)
          Y[(size_t)(b * SS + trow(f, i)) * HH + o] = acc[bt][r] + bs;
      }
    }
  }
}

__global__ __launch_bounds__(1024) void proj_f32_kernel(const float* __restrict__ Xin,
                                                        const float* __restrict__ Wo,
                                                        const float* __restrict__ bo,
                                                        float* __restrict__ out) {
  __shared__ float xs[8][HH];
  const int chunk = blockIdx.x >> 1;
  const int oc = blockIdx.x & 1;
  const int tid = threadIdx.x;
  const int NROW = BB * SS;
  {
    const int r = tid >> 7, c4 = (tid & 127) << 2;
    const int row = chunk * 8 + r;
    if (row < NROW)
      *(float4*)&xs[r][c4] = *(const float4*)(Xin + (size_t)row * HH + c4);
  }
  __syncthreads();
  const int wid = tid >> 6, lane = tid & 63;
  const int og = lane >> 3, kg = lane & 7;
  const int o0 = oc * 256 + wid * 16;
  const int kbase = kg * 4;
  float acc[2][8];
#pragma unroll
  for (int bt = 0; bt < 2; ++bt)
#pragma unroll
    for (int r = 0; r < 8; ++r) acc[bt][r] = 0.f;
#pragma unroll
  for (int i = 0; i < 16; ++i) {
    float4 x4[8];
#pragma unroll
    for (int r = 0; r < 8; ++r) x4[r] = *(const float4*)&xs[r][kbase + i * 32];
#pragma unroll
    for (int bt = 0; bt < 2; ++bt) {
      const float4 w4 =
          *(const float4*)(Wo + (size_t)(o0 + bt * 8 + og) * HH + kbase + i * 32);
#pragma unroll
      for (int r = 0; r < 8; ++r) acc[bt][r] += dot4(w4, x4[r]);
    }
  }
#pragma unroll
  for (int bt = 0; bt < 2; ++bt)
#pragma unroll
    for (int r = 0; r < 8; ++r) acc[bt][r] = kg_reduce8(acc[bt][r]);
  if (kg == 0) {
#pragma unroll
    for (int bt = 0; bt < 2; ++bt) {
      const int o = o0 + bt * 8 + og;
      const float bias = bo[o];
#pragma unroll
      for (int r = 0; r < 8; ++r) {
        int row = chunk * 8 + r;
        if (row < NROW) out[(size_t)row * HH + o] = acc[bt][r] + bias;
      }
    }
  }
}

__global__ __launch_bounds__(256) void fallback_aux_kernel(
    const float* __restrict__ Vp, float* __restrict__ vsum,
    const uint4* __restrict__ gv, int* __restrict__ flag) {
  if (blockIdx.x < 4) {
    const int oid = blockIdx.x * 256 + threadIdx.x;
    const int b = oid >> 9, o = oid & 511;
    float acc = 0.f;
    for (int t = 0; t < SS; ++t) acc += Vp[(size_t)(b * SS + t) * HH + o];
    vsum[oid] = acc;
  } else {
    __shared__ int s;
    if (threadIdx.x == 0) s = 0;
    __syncthreads();
    unsigned int local = 0;
    for (int i = threadIdx.x; i < 2048; i += 256) {
      uint4 v = gv[i];
      local |= (v.x | v.y | v.z | v.w) & 0x0000ff00u;
    }
    if (local) atomicOr(&s, 1);
    __syncthreads();
    if (threadIdx.x == 0) *flag = s;
  }
}

// ---------------------------------------------------------------------------
extern "C" void kernel_launch(void* const* d_in, const int* in_sizes, int n_in,
                              void* d_out, int out_size, void* d_ws, size_t ws_size,
                              hipStream_t stream) {
  (void)in_sizes; (void)n_in; (void)out_size;
  const float* query = (const float*)d_in[0];
  const float* key   = (const float*)d_in[1];
  const float* value = (const float*)d_in[2];
  const void*  graph = d_in[3];
  const float* EK = (const float*)d_in[4];
  const float* EV = (const float*)d_in[5];
  const float* EQ = (const float*)d_in[6];
  const float* Wq = (const float*)d_in[7];
  const float* bq = (const float*)d_in[8];
  const float* Wk = (const float*)d_in[9];
  const float* bk = (const float*)d_in[10];
  const float* Wv = (const float*)d_in[11];
  const float* bv = (const float*)d_in[12];
  const float* Wo = (const float*)d_in[13];
  const float* bo = (const float*)d_in[14];
  float* out = (float*)d_out;

  char* ws = (char*)d_ws;
  int*   flag = (int*)ws;
  float* vsum = (float*)(ws + OFF_VSUM);
  float* xsumVp = (float*)(ws + OFF_XSUM);
  float* Qp = (float*)(ws + OFF_QP);
  float* Kp = (float*)(ws + OFF_KP);
  float* Vp = (float*)(ws + OFF_VP);
  float* Xp = (float*)(ws + OFF_XPP);
  ushort_t* WBF = (ushort_t*)(ws + OFF_WBF);

  const bool useMfma = ws_size >= WS_NEED;

  if (useMfma) {
    prepare_kernel<<<2129, 256, 0, stream>>>(Wq, Wk, Wv, Wo, WBF, value, xsumVp,
                                             (const uint4*)graph, flag);
    gemm_prep_kernel<<<240, 256, 0, stream>>>(WBF, query, key, value,
                                              bq, bk, bv, Wv, xsumVp,
                                              Qp, Kp, Vp, vsum);
    attn_fused_kernel<<<1086, 256, 0, stream>>>(Qp, Kp, Vp, vsum, graph, flag,
                                                EK, EV, EQ, Xp);
    gemm_proj_kernel<<<66, 256, 0, stream>>>(WBF, Xp, bo, out);
  } else {
    prep_f32_kernel<<<480, 1024, 0, stream>>>(query, key, value, Wq, Wk, Wv,
                                              bq, bk, bv, Qp, Kp, Vp);
    fallback_aux_kernel<<<5, 256, 0, stream>>>(Vp, vsum, (const uint4*)graph, flag);
    attn_fused_kernel<<<1086, 256, 0, stream>>>(Qp, Kp, Vp, vsum, graph, flag,
                                                EK, EV, EQ, Xp);
    proj_f32_kernel<<<258, 1024, 0, stream>>>(Xp, Wo, bo, out);
  }
}